// Round 6
// baseline (128.601 us; speedup 1.0000x reference)
//
#include <hip/hip_runtime.h>

#define SQ 4096
#define NB 2
#define NH 4
#define DH 32
#define DM 128

typedef float f32x16 __attribute__((ext_vector_type(16)));
typedef float f32x4  __attribute__((ext_vector_type(4)));
typedef __bf16 bf16x8 __attribute__((ext_vector_type(8)));
typedef unsigned int uint4v __attribute__((ext_vector_type(4)));
typedef unsigned short u16;

union B8 { uint4v u; bf16x8 b; };

__device__ inline u16 f2bf(float x) {
  unsigned u = __builtin_bit_cast(unsigned, x);
  unsigned r = (u + 0x7FFF + ((u >> 16) & 1)) >> 16;
  return (u16)r;
}

__device__ inline unsigned cvt_pk_bf16(float a, float b) {
  unsigned r;
  asm("v_cvt_pk_bf16_f32 %0, %1, %2" : "=v"(r) : "v"(a), "v"(b));
  return r;
}

__device__ inline void swap32(unsigned &a, unsigned &b) {
  asm("v_permlane32_swap_b32 %0, %1" : "+v"(a), "+v"(b));
}

#if __has_builtin(__builtin_amdgcn_exp2f)
#define EX2 __builtin_amdgcn_exp2f
#else
#define EX2 exp2f
#endif

__device__ inline float xhalf_max(float x) {
  unsigned ua = __builtin_bit_cast(unsigned, x), ub = ua;
  asm("v_permlane32_swap_b32 %0, %1" : "+v"(ua), "+v"(ub));
  return fmaxf(__builtin_bit_cast(float, ua), __builtin_bit_cast(float, ub));
}

__device__ inline float xhalf_add(float x) {
  unsigned ua = __builtin_bit_cast(unsigned, x), ub = ua;
  asm("v_permlane32_swap_b32 %0, %1" : "+v"(ua), "+v"(ub));
  return __builtin_bit_cast(float, ua) + __builtin_bit_cast(float, ub);
}

// max of 16 via v_max3 fusion (nested fmax triples)
__device__ inline float tmax16(const f32x16& v) {
  float a0 = fmaxf(fmaxf(v[0], v[1]), v[2]);
  float a1 = fmaxf(fmaxf(v[3], v[4]), v[5]);
  float a2 = fmaxf(fmaxf(v[6], v[7]), v[8]);
  float a3 = fmaxf(fmaxf(v[9], v[10]), v[11]);
  float a4 = fmaxf(fmaxf(v[12], v[13]), v[14]);
  float b0 = fmaxf(fmaxf(a0, a1), a2);
  float b1 = fmaxf(fmaxf(a3, a4), v[15]);
  return fmaxf(b0, b1);
}

// load 8 consecutive fp32, convert to bf16x8 fragment
__device__ inline bf16x8 ld_cvt8(const float* p) {
  f32x4 a = *(const f32x4*)p;
  f32x4 b = *(const f32x4*)(p + 4);
  B8 r;
  r.u[0] = cvt_pk_bf16(a[0], a[1]);
  r.u[1] = cvt_pk_bf16(a[2], a[3]);
  r.u[2] = cvt_pk_bf16(b[0], b[1]);
  r.u[3] = cvt_pk_bf16(b[2], b[3]);
  return r.b;
}

// ---------------- K1: prep — xsum (128 blk) + Wo bf16 (1 blk)
__global__ __launch_bounds__(256) void kprep(const float* __restrict__ x,
                                             const float* __restrict__ Wo,
                                             u16* __restrict__ wob,
                                             float* __restrict__ xsum) {
  const int bid = blockIdx.x, t = threadIdx.x;
  if (bid < 128) {
    // xsum: 128 blocks x 64 rows
    const int b = bid >> 6, rblk = bid & 63;
    const int d = t & 127, rh = t >> 7;
    const float* xp = x + ((size_t)b * SQ + rblk * 64) * DM + d;
    float a = 0.f;
    for (int r = rh; r < 64; r += 2) a += xp[(size_t)r * DM];
    __shared__ float red[2][DM];
    red[rh][d] = a;
    __syncthreads();
    if (t < DM) atomicAdd(&xsum[b * DM + t], red[0][t] + red[1][t]);
  } else {
    for (int i = t; i < DM * DM; i += 256) wob[i] = f2bf(Wo[i]);
  }
}

// ---------------- K2: MFMA projections from fp32 x/W, inline cvt (+ fused cvec at by==12)
// qb/kb: bf16 [bh][p][dh]; vt: bf16 [bh][ptile][dh][p%32]
__global__ __launch_bounds__(256) void kprojc(const float* __restrict__ x,
                                              const float* __restrict__ Wk,
                                              const float* __restrict__ Wq,
                                              const float* __restrict__ Wv,
                                              const float* __restrict__ Wo,
                                              const float* __restrict__ xsum,
                                              u16* __restrict__ qb,
                                              u16* __restrict__ kb,
                                              u16* __restrict__ vt,
                                              float* __restrict__ cvec) {
  const int by = blockIdx.y;
  const int t = threadIdx.x;
  if (by == 12) {
    // cvec: c[b][d] = 0.5 * Wo @ (Wv @ xsum)
    if (blockIdx.x >= NB) return;
    const int b = blockIdx.x;
    __shared__ float xs[DM], vs[DM];
    if (t < DM) xs[t] = xsum[b * DM + t];
    __syncthreads();
    const int c = t >> 1, half = t & 1;
    float a = 0.f;
    const float* wr = Wv + c * DM + half * 64;
    const float* xh = xs + half * 64;
    for (int i = 0; i < 64; ++i) a += wr[i] * xh[i];
    a += __shfl_xor(a, 1, 64);
    if (half == 0) vs[c] = a;
    __syncthreads();
    float a2 = 0.f;
    const float* wr2 = Wo + c * DM + half * 64;
    const float* vh = vs + half * 64;
    for (int i = 0; i < 64; ++i) a2 += wr2[i] * vh[i];
    a2 += __shfl_xor(a2, 1, 64);
    if (half == 0) cvec[b * DM + c] = 0.5f * a2;
    return;
  }
  const int lane = t & 63, wid = t >> 6;
  const int l31 = lane & 31, hi = lane >> 5;
  const int mat = by >> 2, h = by & 3;   // 0:K 1:Q 2:V
  const int p0 = (blockIdx.x * 4 + wid) * 32;
  const float* xrow = x + (size_t)(p0 + l31) * DM + 8 * hi;
  const float* W = (mat == 0) ? Wk : (mat == 1 ? Wq : Wv);
  const float* wrow = W + (h * 32 + l31) * DM + 8 * hi;
  f32x16 acc;
#pragma unroll
  for (int r = 0; r < 16; ++r) acc[r] = 0.f;
#pragma unroll
  for (int ks = 0; ks < 8; ++ks) {
    bf16x8 af = ld_cvt8(xrow + ks * 16);
    bf16x8 wf = ld_cvt8(wrow + ks * 16);
    acc = __builtin_amdgcn_mfma_f32_32x32x16_bf16(af, wf, acc, 0, 0, 0);
  }
  const float QS = 1.4426950408889634f / 5.656854249492380f;
  const int b = p0 >> 12, pl = p0 & (SQ - 1);
  const size_t bh = (size_t)b * NH + h;
  if (mat == 0) {
    u16* dst = kb + (bh * SQ + pl) * DH + l31;
#pragma unroll
    for (int r = 0; r < 16; ++r) {
      int row = (r & 3) + 8 * (r >> 2) + 4 * hi;
      dst[(size_t)row * DH] = f2bf(acc[r]);
    }
  } else if (mat == 1) {
    u16* dst = qb + (bh * SQ + pl) * DH + l31;
#pragma unroll
    for (int r = 0; r < 16; ++r) {
      int row = (r & 3) + 8 * (r >> 2) + 4 * hi;
      dst[(size_t)row * DH] = f2bf(acc[r] * QS);
    }
  } else {
    u16* dst = vt + ((bh * (SQ / 32) + (pl >> 5)) * DH + l31) * 32;
#pragma unroll
    for (int r = 0; r < 16; ++r) {
      int row = (r & 3) + 8 * (r >> 2) + 4 * hi;
      dst[row] = f2bf(acc[r]);
    }
  }
}

// ---------------- K3: fused attention, 32 q per wave, keys 4-way split, 1024 blocks
#define TILE(K0, K1, V0, V1, NOFF) {                                               \
  __builtin_amdgcn_s_setprio(1);                                                   \
  f32x16 sc = __builtin_amdgcn_mfma_f32_32x32x16_bf16(K0.b, qf0.b, zacc, 0, 0, 0); \
  sc = __builtin_amdgcn_mfma_f32_32x32x16_bf16(K1.b, qf1.b, sc, 0, 0, 0);          \
  __builtin_amdgcn_s_setprio(0);                                                   \
  K0.u = *(const uint4v*)(kT + (NOFF));                                            \
  K1.u = *(const uint4v*)(kT + (NOFF) + 16);                                       \
  float pm = xhalf_max(tmax16(sc));                                                \
  if (__any(pm > m + 8.f)) {                                                       \
    float n = fmaxf(m, pm);                                                        \
    float rs = EX2(m - n);                                                         \
    s *= rs;                                                                       \
    _Pragma("unroll") for (int r = 0; r < 16; ++r) acc[r] *= rs;                   \
    m = n;                                                                         \
  }                                                                                \
  float p_[16];                                                                    \
  _Pragma("unroll") for (int r = 0; r < 16; ++r) p_[r] = EX2(sc[r] - m);           \
  float ls = ((p_[0]+p_[1])+(p_[2]+p_[3]))+((p_[4]+p_[5])+(p_[6]+p_[7]));          \
  ls += ((p_[8]+p_[9])+(p_[10]+p_[11]))+((p_[12]+p_[13])+(p_[14]+p_[15]));         \
  s += xhalf_add(ls);                                                              \
  unsigned w0 = cvt_pk_bf16(p_[0], p_[1]),  w1 = cvt_pk_bf16(p_[2], p_[3]);        \
  unsigned w2 = cvt_pk_bf16(p_[4], p_[5]),  w3 = cvt_pk_bf16(p_[6], p_[7]);        \
  unsigned w4 = cvt_pk_bf16(p_[8], p_[9]),  w5 = cvt_pk_bf16(p_[10], p_[11]);      \
  unsigned w6 = cvt_pk_bf16(p_[12], p_[13]), w7 = cvt_pk_bf16(p_[14], p_[15]);     \
  swap32(w0, w2); swap32(w1, w3); swap32(w4, w6); swap32(w5, w7);                  \
  B8 bp0_, bp1_;                                                                   \
  bp0_.u[0] = w0; bp0_.u[1] = w1; bp0_.u[2] = w2; bp0_.u[3] = w3;                  \
  bp1_.u[0] = w4; bp1_.u[1] = w5; bp1_.u[2] = w6; bp1_.u[3] = w7;                  \
  __builtin_amdgcn_s_setprio(1);                                                   \
  acc = __builtin_amdgcn_mfma_f32_32x32x16_bf16(V0.b, bp0_.b, acc, 0, 0, 0);       \
  acc = __builtin_amdgcn_mfma_f32_32x32x16_bf16(V1.b, bp1_.b, acc, 0, 0, 0);       \
  __builtin_amdgcn_s_setprio(0);                                                   \
  V0.u = *(const uint4v*)(vT + (NOFF));                                            \
  V1.u = *(const uint4v*)(vT + (NOFF) + 16);                                       \
}

__global__ __launch_bounds__(256, 4) void kattn(const u16* __restrict__ qb,
                                                const u16* __restrict__ kb,
                                                const u16* __restrict__ vt,
                                                u16* __restrict__ yb) {
  __shared__ float sm_[3][64], ss_[3][64], sa_[3][16][64];
  const int t = threadIdx.x, lane = t & 63, wid = t >> 6;
  const int l31 = lane & 31, hi = lane >> 5;
  // XCD-locality: consecutive block ids round-robin XCDs; bh = id&7 pins each
  // (b,h)'s K/V (512KB) into one XCD's L2.
  const int bh = blockIdx.x & 7;
  const int qbase = (blockIdx.x >> 3) * 32;

  const u16* qrow = qb + ((size_t)bh * SQ + qbase + l31) * DH + 8 * hi;
  B8 qf0, qf1;
  qf0.u = *(const uint4v*)(qrow);
  qf1.u = *(const uint4v*)(qrow + 16);

  const int kh = wid;  // key quarter: 1024 keys per wave
  const u16* kT = kb + ((size_t)bh * SQ + kh * 1024) * DH + l31 * 32 + 8 * hi;
  const u16* vT = vt + ((size_t)bh * (SQ / 32) + kh * 32) * (DH * 32) + l31 * 32 + 8 * hi;

  f32x16 zacc, acc;
#pragma unroll
  for (int r = 0; r < 16; ++r) { zacc[r] = 0.f; acc[r] = 0.f; }
  float m = -1e30f, s = 0.f;

  B8 ka0, ka1, va0, va1, kb0, kb1, vb0, vb1;
  ka0.u = *(const uint4v*)(kT);        ka1.u = *(const uint4v*)(kT + 16);
  va0.u = *(const uint4v*)(vT);        va1.u = *(const uint4v*)(vT + 16);
  kb0.u = *(const uint4v*)(kT + 1024); kb1.u = *(const uint4v*)(kT + 1024 + 16);
  vb0.u = *(const uint4v*)(vT + 1024); vb1.u = *(const uint4v*)(vT + 1024 + 16);

  for (int ti = 0; ti < 32; ti += 2) {
    const int off = ti << 10;
    TILE(ka0, ka1, va0, va1, off + 2048)   // last-iter over-read stays inside ws (next region)
    TILE(kb0, kb1, vb0, vb1, off + 3072)
  }

  if (wid) {
    const int w = wid - 1;
    sm_[w][lane] = m;
    ss_[w][lane] = s;
#pragma unroll
    for (int r = 0; r < 16; ++r) sa_[w][r][lane] = acc[r];
  }
  __syncthreads();
  if (wid == 0) {
    float mm = m;
#pragma unroll
    for (int w = 0; w < 3; ++w) mm = fmaxf(mm, sm_[w][lane]);
    float e = EX2(m - mm);
    float den = s * e;
    float ew[3];
#pragma unroll
    for (int w = 0; w < 3; ++w) {
      ew[w] = EX2(sm_[w][lane] - mm);
      den += ss_[w][lane] * ew[w];
    }
    float inv = 0.5f / den;
    const int b = bh >> 2, h = bh & 3;
    u16* yp = yb + ((size_t)(b * SQ) + qbase + l31) * DM + h * 32;
#pragma unroll
    for (int r = 0; r < 16; ++r) {
      float o = acc[r] * e;
#pragma unroll
      for (int w = 0; w < 3; ++w) o += sa_[w][r][lane] * ew[w];
      int row = (r & 3) + 8 * (r >> 2) + 4 * hi;  // f offset within head
      yp[row] = f2bf(o * inv);
    }
  }
}

// ---------------- K4 (MFMA): out[b,p,d] = sum_f yb[b,p,f]*Wo[d,f] + cvec[b,d]
__global__ __launch_bounds__(256) void kout(const u16* __restrict__ yb,
                                            const u16* __restrict__ wob,
                                            const float* __restrict__ cvec,
                                            float* __restrict__ out) {
  const int t = threadIdx.x, lane = t & 63, wid = t >> 6;
  const int l31 = lane & 31, hi = lane >> 5;
  const int blk = blockIdx.x;          // 256 blocks: [b(1)][ptile(128)]
  const int b = blk >> 7;
  const int p0 = (blk & 127) * 32;
  const int d0 = wid * 32;             // each wave: one 32-col d-tile
  const u16* yrow = yb + ((size_t)(b * SQ) + p0 + l31) * DM + 8 * hi;
  const u16* wrow = wob + (size_t)(d0 + l31) * DM + 8 * hi;
  f32x16 acc;
#pragma unroll
  for (int r = 0; r < 16; ++r) acc[r] = 0.f;
#pragma unroll
  for (int ks = 0; ks < 8; ++ks) {
    B8 a, w;
    a.u = *(const uint4v*)(yrow + ks * 16);
    w.u = *(const uint4v*)(wrow + ks * 16);
    acc = __builtin_amdgcn_mfma_f32_32x32x16_bf16(a.b, w.b, acc, 0, 0, 0);
  }
  float cv = cvec[b * DM + d0 + l31];
  float* op = out + ((size_t)(b * SQ) + p0) * DM + d0 + l31;
#pragma unroll
  for (int r = 0; r < 16; ++r) {
    int row = (r & 3) + 8 * (r >> 2) + 4 * hi;  // p offset
    op[(size_t)row * DM] = acc[r] + cv;
  }
}

extern "C" void kernel_launch(void* const* d_in, const int* in_sizes, int n_in,
                              void* d_out, int out_size, void* d_ws, size_t ws_size,
                              hipStream_t stream) {
  const float* x  = (const float*)d_in[0];
  const float* Wk = (const float*)d_in[1];
  const float* Wq = (const float*)d_in[2];
  const float* Wv = (const float*)d_in[3];
  const float* Wo = (const float*)d_in[4];
  float* out = (float*)d_out;
  char* ws = (char*)d_ws;
  // layout (8.25 MB total, proven-safe):
  //   aux 256KB: xsum @0 (1K), cvec @4K (1K), wob @64K (32K)
  //   qb @256K (2M), kb (2M), vt (2M), yb (2M)
  float* xsum = (float*)(ws);
  float* cvec = (float*)(ws + (4 << 10));
  u16* wob = (u16*)(ws + (64 << 10));
  u16* qb = (u16*)(ws + (256 << 10));
  u16* kb = (u16*)(ws + (256 << 10) + ((size_t)2 << 20));
  u16* vt = (u16*)(ws + (256 << 10) + ((size_t)4 << 20));
  u16* yb = (u16*)(ws + (256 << 10) + ((size_t)6 << 20));

  hipMemsetAsync(xsum, 0, NB * DM * sizeof(float), stream);
  kprep<<<dim3(129), dim3(256), 0, stream>>>(x, Wo, wob, xsum);
  kprojc<<<dim3(64, 13), dim3(256), 0, stream>>>(x, Wk, Wq, Wv, Wo, xsum, qb, kb, vt, cvec);
  kattn<<<dim3(1024), dim3(256), 0, stream>>>(qb, kb, vt, yb);
  kout<<<dim3(256), dim3(256), 0, stream>>>(yb, wob, cvec, out);
}